// Round 3
// baseline (70.968 us; speedup 1.0000x reference)
//
#include <hip/hip_runtime.h>

// 8-qubit VQC, CNOT chains folded into RX pairing masks (validated R2).
// New layout: 8 batch elements per wave64 — one per 8-lane group.
// amp idx x = l3*32 + r (l3 = lane&7, r = reg 0..31):
//   x0<->lane bit2, x1<->lane bit1, x2<->lane bit0,
//   x3<->reg bit4, x4<->reg bit3, x5<->reg bit2, x6<->reg bit1, x7<->reg bit0
// Only 6 of 16 gates are cross-lane (masks < 8 -> one ds_swizzle serves all
// 8 elements); 10 gates are pure register ops. Layer-1 RX_q pairs e_q^e_{q+1},
// layer-2 pairs e_q^e_{q+2} (e_8+=0); <Z_q> sign = parity of {x_i: i<=q, i==q mod 2}.

template<int OFF>
__device__ __forceinline__ float swz(float x) {
    return __int_as_float(__builtin_amdgcn_ds_swizzle(__float_as_int(x), OFF));
}
// xor-swizzle offset: (M<<10)|0x1F.  broadcast lane j within 8-group: (j<<5)|0x18.

constexpr int hibit(int m) { return m >= 16 ? 16 : m >= 8 ? 8 : m >= 4 ? 4 : m >= 2 ? 2 : 1; }

// RX-type mixing along (LM lane-bits, RM reg-bits): new = c*a - i*s*partner
template<int LM, int RM>
__device__ __forceinline__ void gate(float re[32], float im[32], float cg, float sg) {
    if constexpr (RM == 0) {
#pragma unroll
        for (int r = 0; r < 32; ++r) {
            const float pr = swz<(LM << 10) | 0x1F>(re[r]);
            const float pi = swz<(LM << 10) | 0x1F>(im[r]);
            const float nr = cg * re[r] + sg * pi;
            const float ni = cg * im[r] - sg * pr;
            re[r] = nr; im[r] = ni;
        }
    } else {
        constexpr int HB = hibit(RM);
#pragma unroll
        for (int a = 0; a < 32; ++a) {
            if (a & HB) continue;                // closed pair {a, b}, a < b
            const int b = a ^ RM;
            float pra, pia, prb, pib;
            if constexpr (LM != 0) {
                prb = swz<(LM << 10) | 0x1F>(re[b]); pib = swz<(LM << 10) | 0x1F>(im[b]);
                pra = swz<(LM << 10) | 0x1F>(re[a]); pia = swz<(LM << 10) | 0x1F>(im[a]);
            } else {
                prb = re[b]; pib = im[b]; pra = re[a]; pia = im[a];
            }
            const float nra = cg * re[a] + sg * pib;
            const float nia = cg * im[a] - sg * prb;
            const float nrb = cg * re[b] + sg * pia;
            const float nib = cg * im[b] - sg * pra;
            re[a] = nra; im[a] = nia; re[b] = nrb; im[b] = nib;
        }
    }
}

__global__ __launch_bounds__(256, 4) void vqc_kernel(
    const float* __restrict__ inputs,   // (B, 8)
    const float* __restrict__ weights,  // (2, 8)
    float* __restrict__ out)            // (B, 8)
{
    const int tid = threadIdx.x;
    const int l3 = tid & 7;
    const int e = (blockIdx.x << 5) + (tid >> 3);     // this group's batch element

    // ---- per-element trig, lane-parallel: lane j of each group does angle j ----
    const float ang = inputs[(blockIdx.x << 8) + tid];  // coalesced
    const float ch = __cosf(0.5f * ang);
    const float sh = __sinf(0.5f * ang);

    // broadcast (c_j, s_j) to all 8 lanes of the group
    float bc[8], bs[8];
#pragma unroll
    for (int j = 0; j < 8; ++j) {
        bc[j] = swz<(0 << 10) | 0x18 | 0x00>(ch);  // placeholder, specialized below
    }
    // (manual unroll: template arg must be literal per j)
    bc[0] = swz<(0 << 5) | 0x18>(ch); bs[0] = swz<(0 << 5) | 0x18>(sh);
    bc[1] = swz<(1 << 5) | 0x18>(ch); bs[1] = swz<(1 << 5) | 0x18>(sh);
    bc[2] = swz<(2 << 5) | 0x18>(ch); bs[2] = swz<(2 << 5) | 0x18>(sh);
    bc[3] = swz<(3 << 5) | 0x18>(ch); bs[3] = swz<(3 << 5) | 0x18>(sh);
    bc[4] = swz<(4 << 5) | 0x18>(ch); bs[4] = swz<(4 << 5) | 0x18>(sh);
    bc[5] = swz<(5 << 5) | 0x18>(ch); bs[5] = swz<(5 << 5) | 0x18>(sh);
    bc[6] = swz<(6 << 5) | 0x18>(ch); bs[6] = swz<(6 << 5) | 0x18>(sh);
    bc[7] = swz<(7 << 5) | 0x18>(ch); bs[7] = swz<(7 << 5) | 0x18>(sh);

    // ---- initial product state RY(x)|0..0> (all real) ----
    const float v0 = (l3 & 4) ? bs[0] : bc[0];
    const float v1 = (l3 & 2) ? bs[1] : bc[1];
    const float v2 = (l3 & 1) ? bs[2] : bc[2];
    const float lp = v0 * v1 * v2;

    float t4[4], t8[8], t16[16];
    t4[0] = bc[6] * bc[7]; t4[1] = bc[6] * bs[7];
    t4[2] = bs[6] * bc[7]; t4[3] = bs[6] * bs[7];
#pragma unroll
    for (int k = 0; k < 4; ++k) { t8[k] = bc[5] * t4[k]; t8[4 + k] = bs[5] * t4[k]; }
#pragma unroll
    for (int k = 0; k < 8; ++k) { t16[k] = bc[4] * t8[k]; t16[8 + k] = bs[4] * t8[k]; }
    const float lpc = lp * bc[3], lps = lp * bs[3];
    float re[32], im[32];
#pragma unroll
    for (int k = 0; k < 16; ++k) { re[k] = lpc * t16[k]; re[16 + k] = lps * t16[k]; }

    // ---- weight trig, layer 1 (wave-uniform) ----
    float tc[8], ts[8];
#pragma unroll
    for (int j = 0; j < 8; ++j) {
        const float x = 0.5f * weights[j];
        tc[j] = __cosf(x); ts[j] = __sinf(x);
    }

    // ---- layer 1 (masks e_q ^ e_{q+1}) ----
    // q0: LM=6, specialized for im == 0
#pragma unroll
    for (int r = 0; r < 32; ++r) {
        const float pr = swz<(6 << 10) | 0x1F>(re[r]);
        im[r] = -ts[0] * pr;
        re[r] = tc[0] * re[r];
    }
    gate<3, 0 >(re, im, tc[1], ts[1]);   // q1: lanes {1,0}
    gate<1, 16>(re, im, tc[2], ts[2]);   // q2: lane0 + reg bit4
    gate<0, 24>(re, im, tc[3], ts[3]);   // q3: regs {4,3}
    gate<0, 12>(re, im, tc[4], ts[4]);   // q4
    gate<0, 6 >(re, im, tc[5], ts[5]);   // q5
    gate<0, 3 >(re, im, tc[6], ts[6]);   // q6
    gate<0, 1 >(re, im, tc[7], ts[7]);   // q7

    // ---- weight trig, layer 2 ----
#pragma unroll
    for (int j = 0; j < 8; ++j) {
        const float x = 0.5f * weights[8 + j];
        tc[j] = __cosf(x); ts[j] = __sinf(x);
    }

    // ---- layer 2 (masks e_q ^ e_{q+2}, e_8+ = 0) ----
    gate<5, 0 >(re, im, tc[0], ts[0]);   // q0: lanes {2,0}
    gate<2, 16>(re, im, tc[1], ts[1]);   // q1: lane1 + reg bit4
    gate<1, 8 >(re, im, tc[2], ts[2]);   // q2: lane0 + reg bit3
    gate<0, 20>(re, im, tc[3], ts[3]);   // q3: regs {4,2}
    gate<0, 10>(re, im, tc[4], ts[4]);   // q4
    gate<0, 5 >(re, im, tc[5], ts[5]);   // q5
    gate<0, 2 >(re, im, tc[6], ts[6]);   // q6: e6 alone
    gate<0, 1 >(re, im, tc[7], ts[7]);   // q7: e7 alone

    // ---- measurement ----
    float p[32];
#pragma unroll
    for (int r = 0; r < 32; ++r) p[r] = re[r] * re[r] + im[r] * im[r];

    // reg-side signed folds. Sign sets on reg bits (bit4=x3..bit0=x7):
    // A:none  P1:{4}  P2:{3}  P3:{4,2}  P4:{3,1}  P5:{4,2,0}
    float u[16], v[16];
#pragma unroll
    for (int k = 0; k < 16; ++k) { u[k] = p[2 * k] + p[2 * k + 1]; v[k] = p[2 * k] - p[2 * k + 1]; }
    float uu[8], ud[8], vu[8];
#pragma unroll
    for (int k = 0; k < 8; ++k) {
        uu[k] = u[2 * k] + u[2 * k + 1];
        ud[k] = u[2 * k] - u[2 * k + 1];
        vu[k] = v[2 * k] + v[2 * k + 1];
    }
    float uuu[4], uud[4], udu[4], vud[4];
#pragma unroll
    for (int k = 0; k < 4; ++k) {
        uuu[k] = uu[2 * k] + uu[2 * k + 1];
        uud[k] = uu[2 * k] - uu[2 * k + 1];
        udu[k] = ud[2 * k] + ud[2 * k + 1];
        vud[k] = vu[2 * k] - vu[2 * k + 1];
    }
    float a2[2], b2[2], c2[2], d2[2], e2[2];
#pragma unroll
    for (int k = 0; k < 2; ++k) {
        a2[k] = uuu[2 * k] + uuu[2 * k + 1];
        b2[k] = uuu[2 * k] - uuu[2 * k + 1];
        c2[k] = uud[2 * k] + uud[2 * k + 1];
        d2[k] = udu[2 * k] - udu[2 * k + 1];
        e2[k] = vud[2 * k] + vud[2 * k + 1];
    }
    float SA = a2[0] + a2[1];   // lane masks: q0@4, q1@2, q2@5
    float S1 = a2[0] - a2[1];   // q3 @ lane-mask 2
    float S2 = b2[0] + b2[1];   // q4 @ 5
    float S3 = c2[0] - c2[1];   // q5 @ 2
    float S4 = d2[0] + d2[1];   // q6 @ 5
    float S5 = e2[0] - e2[1];   // q7 @ 2

    // ---- 3-stage lane WHT within each 8-group: x'(m) = x(m^2^k) + (-1)^{m_k} x(m)
    const float sg0 = (l3 & 1) ? -1.0f : 1.0f;
    const float sg1 = (l3 & 2) ? -1.0f : 1.0f;
    const float sg2 = (l3 & 4) ? -1.0f : 1.0f;
#define WSTAGE(x, M, sgn) { const float b_ = swz<((M) << 10) | 0x1F>(x); x = __builtin_fmaf(sgn, x, b_); }
#define WHT3(x) WSTAGE(x, 1, sg0) WSTAGE(x, 2, sg1) WSTAGE(x, 4, sg2)
    WHT3(SA) WHT3(S1) WHT3(S2) WHT3(S3) WHT3(S4) WHT3(S5)
#undef WHT3
#undef WSTAGE

    float* o = out + (size_t)e * 8;
    if (l3 == 4) {
        o[0] = SA;
    } else if (l3 == 2) {
        o[1] = SA; o[3] = S1; o[5] = S3; o[7] = S5;
    } else if (l3 == 5) {
        o[2] = SA; o[4] = S2; o[6] = S4;
    }
}

extern "C" void kernel_launch(void* const* d_in, const int* in_sizes, int n_in,
                              void* d_out, int out_size, void* d_ws, size_t ws_size,
                              hipStream_t stream) {
    const float* inputs  = (const float*)d_in[0];
    const float* weights = (const float*)d_in[1];
    float* out = (float*)d_out;
    const int B = in_sizes[0] / 8;          // 32768
    hipLaunchKernelGGL(vqc_kernel, dim3(B / 32), dim3(256), 0, stream,
                       inputs, weights, out);
}